// Round 5
// baseline (242.559 us; speedup 1.0000x reference)
//
#include <hip/hip_runtime.h>

typedef __bf16 bf16;
typedef __bf16 bf16x4 __attribute__((ext_vector_type(4)));
typedef __bf16 bf16x8 __attribute__((ext_vector_type(8)));
typedef float f32x4 __attribute__((ext_vector_type(4)));

#define AS1 __attribute__((address_space(1)))
#define AS3 __attribute__((address_space(3)))

__device__ __forceinline__ void async_copy16(const void* g, void* l) {
  // global -> LDS direct, 16B/lane; LDS dest = wave-uniform base + lane*16.
  __builtin_amdgcn_global_load_lds((const AS1 void*)g, (AS3 void*)l, 16, 0, 0);
}

#define BB 8
#define CC 1024
#define QQ 128
#define EE 512
#define HH 1024
#define FOURE 2048

// ---------------------------------------------------------------------------
// prep:
//  bx [0,2048):    W1 (2048x1024) -> W1T
//  bx [2048,4096): W2 (1024x2048) -> W2T
//  bx [4096,4608): question per-batch transpose -> qT
//  bx [4608,5120): qm = question*wmul -> bf16 hi/lo (qmh/qml) + qw row-dots
// ---------------------------------------------------------------------------
__global__ __launch_bounds__(256) void prep_kernel(
    const float* __restrict__ W1, const float* __restrict__ W2,
    const float* __restrict__ qst, const float* __restrict__ wmul,
    const float* __restrict__ wqv, bf16* __restrict__ W1T,
    bf16* __restrict__ W2T, bf16* __restrict__ qT,
    bf16* __restrict__ qmh, bf16* __restrict__ qml, float* __restrict__ qw) {
  __shared__ float tile[32][33];
  __shared__ float r4[4];
  int bx = blockIdx.x;
  int t = threadIdx.x;
  if (bx >= 4608) {
    int i = bx - 4608;
    int half = t >> 7, tr = t & 127;
    int rowg = i * 2 + half;  // 0..1023 over (b,q)
    const float* qrow = qst + (size_t)rowg * EE;
    float4 qv = *(const float4*)&qrow[tr * 4];
    float4 wm4 = *(const float4*)&wmul[tr * 4];
    float4 wq4 = *(const float4*)&wqv[tr * 4];
    float m[4] = {qv.x * wm4.x, qv.y * wm4.y, qv.z * wm4.z, qv.w * wm4.w};
    bf16x4 h, l;
#pragma unroll
    for (int k = 0; k < 4; ++k) {
      bf16 hh = (bf16)m[k];
      h[k] = hh; l[k] = (bf16)(m[k] - (float)hh);
    }
    *(bf16x4*)&qmh[(size_t)rowg * EE + tr * 4] = h;
    *(bf16x4*)&qml[(size_t)rowg * EE + tr * 4] = l;
    float s = qv.x * wq4.x + qv.y * wq4.y + qv.z * wq4.z + qv.w * wq4.w;
#pragma unroll
    for (int off = 32; off; off >>= 1) s += __shfl_xor(s, off);
    if ((t & 63) == 0) r4[t >> 6] = s;
    __syncthreads();
    if (tr == 0) qw[rowg] = r4[half * 2] + r4[half * 2 + 1];
    return;
  }
  const float* src;
  bf16* dst;
  int R, C, idx;
  if (bx < 2048) {
    src = W1; dst = W1T; R = 2048; C = 1024; idx = bx;
  } else if (bx < 4096) {
    src = W2; dst = W2T; R = 1024; C = 2048; idx = bx - 2048;
  } else {
    int i = bx - 4096;
    int b = i >> 6; idx = i & 63;
    src = qst + (size_t)b * QQ * EE; dst = qT + (size_t)b * EE * QQ;
    R = 128; C = 512;
  }
  int ctiles = C >> 5;
  int by = idx / ctiles, cx = idx % ctiles;
  int tx = t & 31, ty = t >> 5;
#pragma unroll
  for (int rr = 0; rr < 4; ++rr)
    tile[ty + rr * 8][tx] = src[(size_t)(by * 32 + ty + rr * 8) * C + cx * 32 + tx];
  __syncthreads();
#pragma unroll
  for (int rr = 0; rr < 4; ++rr)
    dst[(size_t)(cx * 32 + ty + rr * 8) * R + by * 32 + tx] = (bf16)tile[tx][ty + rr * 8];
}

// ---------------------------------------------------------------------------
// fused_att: per (b, 32 ctx-rows): sim (split-bf16 3-MFMA) + qw/cw
//   -> softmax over q (in LDS) -> P (LDS only)
//   -> c2q = P @ question (16x16x32 MFMA, B-frags from L2-resident qT)
//   -> writes att[:, 0:3E] = [ctx | c2q | ctx*c2q] (vectorized via LDS)
//   -> writes smax (for the q2c path).
// Grid (32, 8). LDS ~49 KB -> 3 blocks/CU.
// ---------------------------------------------------------------------------
__global__ __launch_bounds__(256) void fused_att_kernel(
    const float* __restrict__ ctx, const bf16* __restrict__ qmh,
    const bf16* __restrict__ qml, const bf16* __restrict__ qT,
    const float* __restrict__ wc, const float* __restrict__ qw,
    float* __restrict__ smax, bf16* __restrict__ att) {
  int b = blockIdx.y;
  int m0 = blockIdx.x * 32;
  // Union region: stage1 {Ah,Al,Bh,Bl,sim_s} / stage2 {c2q_lds}
  __shared__ __align__(16) char U[37376];
  bf16* Ah = (bf16*)(U);              // 32*32
  bf16* Al = (bf16*)(U + 2048);       // 32*32
  bf16* Bh = (bf16*)(U + 4096);       // 128*32
  bf16* Bl = (bf16*)(U + 12288);      // 128*32
  float(*sim_s)[132] = (float(*)[132])(U + 20480);  // 32 x 132
  bf16* c2q_lds = (bf16*)(U);         // 32 x 520 (stage 2)
  __shared__ float wc_s[EE];
  __shared__ float qw_s[QQ];
  __shared__ float cw_s[32];
  __shared__ bf16 P_lds[32][136];
  int t = threadIdx.x;
  for (int i = t; i < EE; i += 256) wc_s[i] = wc[i];
  if (t < QQ) qw_s[t] = qw[b * QQ + t];
  __syncthreads();
  int wv = t >> 6, ln = t & 63, wm = wv >> 1, wn = wv & 1;
  int rl = ln & 15, kq = ln >> 4;
  f32x4 acc[4] = {};
  const float* Ag = ctx + ((size_t)b * CC + m0) * EE;
  const bf16* Bhg = qmh + (size_t)b * QQ * EE;
  const bf16* Blg = qml + (size_t)b * QQ * EE;
  int arow = t >> 2, acq = t & 3;  // threads 0..127 stage A (4 thr/row)
  float cwp = 0.f;
  for (int k0 = 0; k0 < EE; k0 += 32) {
    if (t < 128) {  // A stage: f32 load, hi/lo repack, cw accumulation
      const float4* s4 = (const float4*)(Ag + (size_t)arow * EE + k0 + acq * 8);
      float4 v0 = s4[0], v1 = s4[1];
      float vals[8] = {v0.x, v0.y, v0.z, v0.w, v1.x, v1.y, v1.z, v1.w};
      bf16x8 h, l;
#pragma unroll
      for (int i = 0; i < 8; ++i) {
        cwp += vals[i] * wc_s[k0 + acq * 8 + i];
        bf16 hh = (bf16)vals[i];
        h[i] = hh; l[i] = (bf16)(vals[i] - (float)hh);
      }
      int sl = (acq ^ ((arow >> 1) & 3)) * 8;
      *(bf16x8*)&Ah[arow * 32 + sl] = h;
      *(bf16x8*)&Al[arow * 32 + sl] = l;
    }
#pragma unroll
    for (int r = 0; r < 2; ++r) {  // B stage: async from precomputed qm hi/lo
      int fb = (r * 4 + wv) * 1024 + ln * 16;
      int row = fb >> 6;
      int cq = ((fb >> 4) & 3) ^ ((row >> 1) & 3);
      async_copy16(Bhg + (size_t)row * EE + k0 + cq * 8, (char*)Bh + fb);
      async_copy16(Blg + (size_t)row * EE + k0 + cq * 8, (char*)Bl + fb);
    }
    __syncthreads();
    bf16x8 ah, al, bh[4], bl[4];
    {
      int r = wm * 16 + rl;
      int sl = (kq ^ ((r >> 1) & 3)) * 8;
      ah = *(const bf16x8*)&Ah[r * 32 + sl];
      al = *(const bf16x8*)&Al[r * 32 + sl];
    }
#pragma unroll
    for (int j = 0; j < 4; ++j) {
      int r = wn * 64 + j * 16 + rl;
      int sl = (kq ^ ((r >> 1) & 3)) * 8;
      bh[j] = *(const bf16x8*)&Bh[r * 32 + sl];
      bl[j] = *(const bf16x8*)&Bl[r * 32 + sl];
    }
#pragma unroll
    for (int j = 0; j < 4; ++j) {
      acc[j] = __builtin_amdgcn_mfma_f32_16x16x32_bf16(ah, bh[j], acc[j], 0, 0, 0);
      acc[j] = __builtin_amdgcn_mfma_f32_16x16x32_bf16(ah, bl[j], acc[j], 0, 0, 0);
      acc[j] = __builtin_amdgcn_mfma_f32_16x16x32_bf16(al, bh[j], acc[j], 0, 0, 0);
    }
    __syncthreads();
  }
  // cw reduce (4 lanes/row, threads 0..127)
  if (t < 128) {
    float s = cwp;
    s += __shfl_xor(s, 1); s += __shfl_xor(s, 2);
    if ((t & 3) == 0) cw_s[arow] = s;
  }
  // spill sim (+qw) to LDS
#pragma unroll
  for (int j = 0; j < 4; ++j) {
    int col = wn * 64 + j * 16 + rl;
    float qv = qw_s[col];
    int rbase = wm * 16 + kq * 4;
#pragma unroll
    for (int r = 0; r < 4; ++r) sim_s[rbase + r][col] = acc[j][r] + qv;
  }
  __syncthreads();
  // softmax over q: 8 threads/row
  {
    int row = t >> 3, cb = t & 7;
    float v[16];
    float mx = -3.4e38f;
#pragma unroll
    for (int k = 0; k < 16; ++k) {
      v[k] = sim_s[row][cb + 8 * k];
      mx = fmaxf(mx, v[k]);
    }
    mx = fmaxf(mx, __shfl_xor(mx, 1));
    mx = fmaxf(mx, __shfl_xor(mx, 2));
    mx = fmaxf(mx, __shfl_xor(mx, 4));
    float sm = 0.f;
#pragma unroll
    for (int k = 0; k < 16; ++k) { v[k] = __expf(v[k] - mx); sm += v[k]; }
    sm += __shfl_xor(sm, 1);
    sm += __shfl_xor(sm, 2);
    sm += __shfl_xor(sm, 4);
    float inv = 1.0f / sm;
#pragma unroll
    for (int k = 0; k < 16; ++k) P_lds[row][cb + 8 * k] = (bf16)(v[k] * inv);
    if (cb == 0) smax[b * CC + m0 + row] = mx + cw_s[row];
  }
  __syncthreads();  // P ready; sim_s/staging dead -> c2q_lds may reuse U
  // stage 2: c2q(32x512) = P(32x128) @ qT(512x128)^T ; wave wv covers 128 cols
  f32x4 acc2[2][8] = {};
  const bf16* qTb = qT + (size_t)b * EE * QQ;
#pragma unroll
  for (int kk = 0; kk < 4; ++kk) {
    bf16x8 af2[2];
#pragma unroll
    for (int i = 0; i < 2; ++i) {
      // two bf16x4 loads (8B-aligned; stride 136 elems breaks 16B alignment)
      bf16x4 lo = *(const bf16x4*)&P_lds[i * 16 + rl][kk * 32 + kq * 8];
      bf16x4 hi = *(const bf16x4*)&P_lds[i * 16 + rl][kk * 32 + kq * 8 + 4];
      af2[i][0] = lo[0]; af2[i][1] = lo[1]; af2[i][2] = lo[2]; af2[i][3] = lo[3];
      af2[i][4] = hi[0]; af2[i][5] = hi[1]; af2[i][6] = hi[2]; af2[i][7] = hi[3];
    }
#pragma unroll
    for (int j = 0; j < 8; ++j) {
      int n = wv * 128 + j * 16 + rl;
      bf16x8 bfr = *(const bf16x8*)&qTb[(size_t)n * QQ + kk * 32 + kq * 8];
#pragma unroll
      for (int i = 0; i < 2; ++i)
        acc2[i][j] = __builtin_amdgcn_mfma_f32_16x16x32_bf16(af2[i], bfr, acc2[i][j], 0, 0, 0);
    }
  }
  // spill c2q frags to LDS (row-major, stride 520)
#pragma unroll
  for (int j = 0; j < 8; ++j) {
    int col = wv * 128 + j * 16 + rl;
#pragma unroll
    for (int i = 0; i < 2; ++i) {
      int rbase = i * 16 + kq * 4;
#pragma unroll
      for (int r = 0; r < 4; ++r)
        c2q_lds[(size_t)(rbase + r) * 520 + col] = (bf16)acc2[i][j][r];
    }
  }
  __syncthreads();
  // vectorized att epilogue: parts 0,1,2 for 32 rows x 512 cols
  {
    int row = t >> 3, c8 = (t & 7) * 64;
    const float* crow = ctx + ((size_t)(b * CC + m0 + row)) * EE;
    bf16* arow_p = att + ((size_t)(b * CC + m0 + row)) * FOURE;
#pragma unroll
    for (int cc = 0; cc < 8; ++cc) {
      int col = c8 + cc * 8;
      bf16x8 q8 = *(const bf16x8*)&c2q_lds[(size_t)row * 520 + col];
      float4 v0 = *(const float4*)&crow[col];
      float4 v1 = *(const float4*)&crow[col + 4];
      float cv[8] = {v0.x, v0.y, v0.z, v0.w, v1.x, v1.y, v1.z, v1.w};
      bf16x8 o0, o2;
#pragma unroll
      for (int k = 0; k < 8; ++k) {
        o0[k] = (bf16)cv[k];
        o2[k] = (bf16)(cv[k] * (float)q8[k]);
      }
      *(bf16x8*)&arow_p[col] = o0;
      *(bf16x8*)&arow_p[EE + col] = q8;
      *(bf16x8*)&arow_p[2 * EE + col] = o2;
    }
  }
}

// ---------------------------------------------------------------------------
// q2c with fused (redundant per-block) softmax over c. Grid 256 = 8b x 32.
// atomicAdd into pre-zeroed q2c.
// ---------------------------------------------------------------------------
__global__ __launch_bounds__(256) void q2c_kernel(
    const float* __restrict__ ctx, const float* __restrict__ smax,
    float* __restrict__ q2c) {
  int b = blockIdx.x >> 5, ch = blockIdx.x & 31;
  int t = threadIdx.x;
  __shared__ float red[256];
  __shared__ float w_s[32];
  float v[4];
  float mx = -3.4e38f;
#pragma unroll
  for (int i = 0; i < 4; ++i) {
    v[i] = smax[b * CC + i * 256 + t];
    mx = fmaxf(mx, v[i]);
  }
  red[t] = mx;
  __syncthreads();
  for (int s = 128; s > 0; s >>= 1) {
    if (t < s) red[t] = fmaxf(red[t], red[t + s]);
    __syncthreads();
  }
  mx = red[0];
  __syncthreads();
  float sm = 0.f;
#pragma unroll
  for (int i = 0; i < 4; ++i) sm += __expf(v[i] - mx);
  red[t] = sm;
  __syncthreads();
  for (int s = 128; s > 0; s >>= 1) {
    if (t < s) red[t] += red[t + s];
    __syncthreads();
  }
  float inv = 1.0f / red[0];
  if (t < 32) w_s[t] = __expf(smax[b * CC + ch * 32 + t] - mx) * inv;
  __syncthreads();
  int e = t * 2;
  const float* cb = ctx + ((size_t)b * CC + ch * 32) * EE;
  float a0 = 0.f, a1 = 0.f;
#pragma unroll 8
  for (int r = 0; r < 32; ++r) {
    float2 vv = *(const float2*)&cb[(size_t)r * EE + e];
    float w = w_s[r];
    a0 += w * vv.x;
    a1 += w * vv.y;
  }
  atomicAdd(&q2c[b * EE + e], a0);
  atomicAdd(&q2c[b * EE + e + 1], a1);
}

// ---------------------------------------------------------------------------
// att part 3: att[:, 3E:4E] = ctx * q2c[b]  (BW-bound)
// ---------------------------------------------------------------------------
__global__ __launch_bounds__(256) void att3_kernel(
    const float* __restrict__ ctx, const float* __restrict__ q2c,
    bf16* __restrict__ att) {
  int idx = blockIdx.x * 256 + threadIdx.x;  // over (row, e/8)
  int row = idx >> 6;
  int e = (idx & 63) * 8;
  int b = row >> 10;
  float4 v0 = *(const float4*)&ctx[(size_t)row * EE + e];
  float4 v1 = *(const float4*)&ctx[(size_t)row * EE + e + 4];
  float4 g0 = *(const float4*)&q2c[b * EE + e];
  float4 g1 = *(const float4*)&q2c[b * EE + e + 4];
  bf16x8 o;
  o[0] = (bf16)(v0.x * g0.x); o[1] = (bf16)(v0.y * g0.y);
  o[2] = (bf16)(v0.z * g0.z); o[3] = (bf16)(v0.w * g0.w);
  o[4] = (bf16)(v1.x * g1.x); o[5] = (bf16)(v1.y * g1.y);
  o[6] = (bf16)(v1.z * g1.z); o[7] = (bf16)(v1.w * g1.w);
  *(bf16x8*)&att[(size_t)row * FOURE + 3 * EE + e] = o;
}

// ---------------------------------------------------------------------------
// bf16 GEMM (R3-proven 16x16x32 config): C = A(MxK) @ Bt(NxK)^T.
// Tile MT x 128, BK=64, async staging + XOR chunk-swizzle, GROUP_M=8 block
// swizzle for B L2 reuse. Requires (M/MT) % 8 == 0.
// ---------------------------------------------------------------------------
template <int MT, int OUT_BF16, int RELU, int HAS_BIAS, int HAS_MASK>
__global__ __launch_bounds__(256) void gemm_bt_kernel(
    const bf16* __restrict__ A, const bf16* __restrict__ Bt,
    const float* __restrict__ bias, const float* __restrict__ mask,
    void* __restrict__ Cout, int M, int N, int K, long sA, long sB, long sC) {
  int b = blockIdx.y;
  A += (size_t)b * sA;
  Bt += (size_t)b * sB;
  int ntiles = N >> 7;
  int tiles_per_g = 8 * ntiles;
  int g = blockIdx.x / tiles_per_g, sub = blockIdx.x % tiles_per_g;
  int mt = g * 8 + (sub & 7), ntb = sub >> 3;
  int m0 = mt * MT, n0 = ntb << 7;
  __shared__ bf16 As[MT * 64];
  __shared__ bf16 Bs[128 * 64];
  int t = threadIdx.x, wv = t >> 6, ln = t & 63;
  int wm = wv >> 1, wn = wv & 1;
  constexpr int MI = MT / 32;
  f32x4 acc[MI][4] = {};
  for (int k0 = 0; k0 < K; k0 += 64) {
#pragma unroll
    for (int r = 0; r < MT / 32; ++r) {
      int fb = (r * 4 + wv) * 1024 + ln * 16;
      int row = fb >> 7;
      int q = ((fb >> 4) & 7) ^ (row & 7);
      async_copy16(A + (size_t)(m0 + row) * K + k0 + q * 8,
                   (char*)As + fb);
    }
#pragma unroll
    for (int r = 0; r < 4; ++r) {
      int fb = (r * 4 + wv) * 1024 + ln * 16;
      int row = fb >> 7;
      int q = ((fb >> 4) & 7) ^ (row & 7);
      async_copy16(Bt + (size_t)(n0 + row) * K + k0 + q * 8,
                   (char*)Bs + fb);
    }
    __syncthreads();
    int rl = ln & 15, kq = ln >> 4;
#pragma unroll
    for (int ks = 0; ks < 2; ++ks) {
      int c = ks * 4 + kq;
      bf16x8 af[MI], bfr[4];
#pragma unroll
      for (int i = 0; i < MI; ++i) {
        int row = wm * (MT / 2) + i * 16 + rl;
        af[i] = *(const bf16x8*)&As[row * 64 + ((c ^ (row & 7)) * 8)];
      }
#pragma unroll
      for (int j = 0; j < 4; ++j) {
        int row = wn * 64 + j * 16 + rl;
        bfr[j] = *(const bf16x8*)&Bs[row * 64 + ((c ^ (row & 7)) * 8)];
      }
#pragma unroll
      for (int i = 0; i < MI; ++i)
#pragma unroll
        for (int j = 0; j < 4; ++j)
          acc[i][j] = __builtin_amdgcn_mfma_f32_16x16x32_bf16(af[i], bfr[j], acc[i][j], 0, 0, 0);
    }
    __syncthreads();
  }
  size_t outbase = (size_t)b * sC;
#pragma unroll
  for (int j = 0; j < 4; ++j) {
    int col = n0 + wn * 64 + j * 16 + (ln & 15);
    float bv = HAS_BIAS ? bias[col] : 0.f;
#pragma unroll
    for (int i = 0; i < MI; ++i) {
      int rbase = m0 + wm * (MT / 2) + i * 16 + ((ln >> 4) << 2);
#pragma unroll
      for (int r = 0; r < 4; ++r) {
        int row = rbase + r;
        float v = acc[i][j][r] + bv;
        if (HAS_MASK) v *= mask[row];
        if (RELU) v = fmaxf(v, 0.f);
        if (OUT_BF16)
          ((bf16*)Cout)[outbase + (size_t)row * N + col] = (bf16)v;
        else
          ((float*)Cout)[outbase + (size_t)row * N + col] = v;
      }
    }
  }
}

// ---------------------------------------------------------------------------
// launcher — 7 dispatches (+1 memset)
// ---------------------------------------------------------------------------
extern "C" void kernel_launch(void* const* d_in, const int* in_sizes, int n_in,
                              void* d_out, int out_size, void* d_ws, size_t ws_size,
                              hipStream_t stream) {
  const float* ctx = (const float*)d_in[0];
  const float* qst = (const float*)d_in[1];
  const float* mask = (const float*)d_in[2];
  const float* wqv = (const float*)d_in[3];
  const float* wcv = (const float*)d_in[4];
  const float* wmul = (const float*)d_in[5];
  const float* W1 = (const float*)d_in[6];
  const float* b1 = (const float*)d_in[7];
  const float* W2 = (const float*)d_in[8];
  const float* b2 = (const float*)d_in[9];
  float* out = (float*)d_out;
  char* ws = (char*)d_ws;

  bf16* att = (bf16*)(ws);                  // 33554432
  bf16* hbuf = (bf16*)(ws + 33554432);      // 16777216
  bf16* W1T = (bf16*)(ws + 50331648);       // 4194304
  bf16* W2T = (bf16*)(ws + 54525952);       // 4194304
  bf16* qT = (bf16*)(ws + 58720256);        // 1048576
  bf16* qmh = (bf16*)(ws + 59768832);       // 1048576
  bf16* qml = (bf16*)(ws + 60817408);       // 1048576
  float* smax = (float*)(ws + 61865984);    // 32768
  float* q2c = (float*)(ws + 61898752);     // 16384
  float* qw = (float*)(ws + 61915136);      // 4096

  prep_kernel<<<5120, 256, 0, stream>>>(W1, W2, qst, wmul, wqv,
                                        W1T, W2T, qT, qmh, qml, qw);
  fused_att_kernel<<<dim3(32, BB), 256, 0, stream>>>(ctx, qmh, qml, qT, wcv,
                                                     qw, smax, att);
  hipMemsetAsync(q2c, 0, BB * EE * sizeof(float), stream);
  q2c_kernel<<<256, 256, 0, stream>>>(ctx, smax, q2c);
  att3_kernel<<<2048, 256, 0, stream>>>(ctx, q2c, att);
  gemm_bt_kernel<64, 1, 0, 1, 1><<<dim3(1024, 1), 256, 0, stream>>>(
      att, W1T, b1, mask, hbuf, 8192, 1024, 2048, 0, 0, 0);
  gemm_bt_kernel<128, 0, 1, 1, 1><<<dim3(1024, 1), 256, 0, stream>>>(
      hbuf, W2T, b2, mask, out, 8192, 2048, 1024, 0, 0, 0);
}

// Round 6
// 229.241 us; speedup vs baseline: 1.0581x; 1.0581x over previous
//
#include <hip/hip_runtime.h>

typedef __bf16 bf16;
typedef __bf16 bf16x2 __attribute__((ext_vector_type(2)));
typedef __bf16 bf16x4 __attribute__((ext_vector_type(4)));
typedef __bf16 bf16x8 __attribute__((ext_vector_type(8)));
typedef float f32x4 __attribute__((ext_vector_type(4)));

#define AS1 __attribute__((address_space(1)))
#define AS3 __attribute__((address_space(3)))

__device__ __forceinline__ void async_copy16(const void* g, void* l) {
  // global -> LDS direct, 16B/lane; LDS dest = wave-uniform base + lane*16.
  __builtin_amdgcn_global_load_lds((const AS1 void*)g, (AS3 void*)l, 16, 0, 0);
}

#define BB 8
#define CC 1024
#define QQ 128
#define EE 512
#define HH 1024
#define FOURE 2048

// ---------------------------------------------------------------------------
// prep:
//  bx [0,2048):    W1 (2048x1024) -> W1T
//  bx [2048,4096): W2 (1024x2048) -> W2T
//  bx [4096,4608): question per-batch transpose -> qT
//  bx [4608,5120): qm = question*wmul -> bf16 hi/lo (qmh/qml) + qw row-dots
// ---------------------------------------------------------------------------
__global__ __launch_bounds__(256) void prep_kernel(
    const float* __restrict__ W1, const float* __restrict__ W2,
    const float* __restrict__ qst, const float* __restrict__ wmul,
    const float* __restrict__ wqv, bf16* __restrict__ W1T,
    bf16* __restrict__ W2T, bf16* __restrict__ qT,
    bf16* __restrict__ qmh, bf16* __restrict__ qml, float* __restrict__ qw) {
  __shared__ float tile[32][33];
  __shared__ float r4[4];
  int bx = blockIdx.x;
  int t = threadIdx.x;
  if (bx >= 4608) {
    int i = bx - 4608;
    int half = t >> 7, tr = t & 127;
    int rowg = i * 2 + half;  // 0..1023 over (b,q)
    const float* qrow = qst + (size_t)rowg * EE;
    float4 qv = *(const float4*)&qrow[tr * 4];
    float4 wm4 = *(const float4*)&wmul[tr * 4];
    float4 wq4 = *(const float4*)&wqv[tr * 4];
    float m[4] = {qv.x * wm4.x, qv.y * wm4.y, qv.z * wm4.z, qv.w * wm4.w};
    bf16x4 h, l;
#pragma unroll
    for (int k = 0; k < 4; ++k) {
      bf16 hh = (bf16)m[k];
      h[k] = hh; l[k] = (bf16)(m[k] - (float)hh);
    }
    *(bf16x4*)&qmh[(size_t)rowg * EE + tr * 4] = h;
    *(bf16x4*)&qml[(size_t)rowg * EE + tr * 4] = l;
    float s = qv.x * wq4.x + qv.y * wq4.y + qv.z * wq4.z + qv.w * wq4.w;
#pragma unroll
    for (int off = 32; off; off >>= 1) s += __shfl_xor(s, off);
    if ((t & 63) == 0) r4[t >> 6] = s;
    __syncthreads();
    if (tr == 0) qw[rowg] = r4[half * 2] + r4[half * 2 + 1];
    return;
  }
  const float* src;
  bf16* dst;
  int R, C, idx;
  if (bx < 2048) {
    src = W1; dst = W1T; R = 2048; C = 1024; idx = bx;
  } else if (bx < 4096) {
    src = W2; dst = W2T; R = 1024; C = 2048; idx = bx - 2048;
  } else {
    int i = bx - 4096;
    int b = i >> 6; idx = i & 63;
    src = qst + (size_t)b * QQ * EE; dst = qT + (size_t)b * EE * QQ;
    R = 128; C = 512;
  }
  int ctiles = C >> 5;
  int by = idx / ctiles, cx = idx % ctiles;
  int tx = t & 31, ty = t >> 5;
#pragma unroll
  for (int rr = 0; rr < 4; ++rr)
    tile[ty + rr * 8][tx] = src[(size_t)(by * 32 + ty + rr * 8) * C + cx * 32 + tx];
  __syncthreads();
#pragma unroll
  for (int rr = 0; rr < 4; ++rr)
    dst[(size_t)(cx * 32 + ty + rr * 8) * R + by * 32 + tx] = (bf16)tile[tx][ty + rr * 8];
}

// ---------------------------------------------------------------------------
// fused_att: per (b, 16 ctx-rows): sim (split-bf16 3-MFMA) + qw/cw
//   -> softmax over q in LDS -> P (LDS) -> c2q = P @ qT^T (MFMA, B from L2)
//   -> att[:, 0:3E] = [ctx | c2q | ctx*c2q] with 256B-contiguous stores.
// Grid (64, 8) = 512 blocks, ~34 KB LDS -> 2 blocks/CU.
// ---------------------------------------------------------------------------
__global__ __launch_bounds__(256) void fused_att_kernel(
    const float* __restrict__ ctx, const bf16* __restrict__ qmh,
    const bf16* __restrict__ qml, const bf16* __restrict__ qT,
    const float* __restrict__ wc, const float* __restrict__ qw,
    float* __restrict__ smax, bf16* __restrict__ att) {
  int b = blockIdx.y;
  int m0 = blockIdx.x * 16;
  // Union: stage1 {Ah,Al,Bh,Bl,sim_s} (26880B) / stage2 {c2q_lds} (16640B)
  __shared__ __align__(16) char U[26880];
  bf16* Ah = (bf16*)(U);                            // 16x32
  bf16* Al = (bf16*)(U + 1024);                     // 16x32
  bf16* Bh = (bf16*)(U + 2048);                     // 128x32
  bf16* Bl = (bf16*)(U + 10240);                    // 128x32
  float(*sim_s)[132] = (float(*)[132])(U + 18432);  // 16 x 132
  bf16* c2q_lds = (bf16*)(U);                       // 16 x 520 (stage 2)
  __shared__ float wc_s[EE];
  __shared__ float qw_s[QQ];
  __shared__ float cw_s[16];
  __shared__ bf16 P_lds[16][136];
  int t = threadIdx.x;
  for (int i = t; i < EE; i += 256) wc_s[i] = wc[i];
  if (t < QQ) qw_s[t] = qw[b * QQ + t];
  __syncthreads();
  int wv = t >> 6, ln = t & 63;
  int rl = ln & 15, kq = ln >> 4;
  f32x4 acc[2] = {};
  const float* Ag = ctx + ((size_t)b * CC + m0) * EE;
  const bf16* Bhg = qmh + (size_t)b * QQ * EE;
  const bf16* Blg = qml + (size_t)b * QQ * EE;
  int arow = t >> 4, ae = (t & 15) * 2;  // A: 2 f32/thread, 16 thr/row
  float cwp = 0.f;
  for (int k0 = 0; k0 < EE; k0 += 32) {
    {  // A stage: f32 float2 load, hi/lo repack, cw accumulation
      float2 v = *(const float2*)(Ag + (size_t)arow * EE + k0 + ae);
      cwp += v.x * wc_s[k0 + ae] + v.y * wc_s[k0 + ae + 1];
      bf16 h0 = (bf16)v.x, h1 = (bf16)v.y;
      bf16x2 h, l;
      h[0] = h0; h[1] = h1;
      l[0] = (bf16)(v.x - (float)h0);
      l[1] = (bf16)(v.y - (float)h1);
      int sl = ((ae >> 3) ^ ((arow >> 1) & 3)) * 8 + (ae & 7);
      *(bf16x2*)&Ah[arow * 32 + sl] = h;
      *(bf16x2*)&Al[arow * 32 + sl] = l;
    }
#pragma unroll
    for (int r = 0; r < 2; ++r) {  // B stage: async from precomputed qm hi/lo
      int fb = (r * 4 + wv) * 1024 + ln * 16;
      int row = fb >> 6;
      int cq = ((fb >> 4) & 3) ^ ((row >> 1) & 3);
      async_copy16(Bhg + (size_t)row * EE + k0 + cq * 8, (char*)Bh + fb);
      async_copy16(Blg + (size_t)row * EE + k0 + cq * 8, (char*)Bl + fb);
    }
    __syncthreads();
    bf16x8 ah, al, bh[2], bl[2];
    {
      int sl = (kq ^ ((rl >> 1) & 3)) * 8;
      ah = *(const bf16x8*)&Ah[rl * 32 + sl];
      al = *(const bf16x8*)&Al[rl * 32 + sl];
    }
#pragma unroll
    for (int j = 0; j < 2; ++j) {
      int r = wv * 32 + j * 16 + rl;
      int sl = (kq ^ ((r >> 1) & 3)) * 8;
      bh[j] = *(const bf16x8*)&Bh[r * 32 + sl];
      bl[j] = *(const bf16x8*)&Bl[r * 32 + sl];
    }
#pragma unroll
    for (int j = 0; j < 2; ++j) {
      acc[j] = __builtin_amdgcn_mfma_f32_16x16x32_bf16(ah, bh[j], acc[j], 0, 0, 0);
      acc[j] = __builtin_amdgcn_mfma_f32_16x16x32_bf16(ah, bl[j], acc[j], 0, 0, 0);
      acc[j] = __builtin_amdgcn_mfma_f32_16x16x32_bf16(al, bh[j], acc[j], 0, 0, 0);
    }
    __syncthreads();
  }
  // cw reduce over the 16 threads of each row
  {
    float s = cwp;
    s += __shfl_xor(s, 1); s += __shfl_xor(s, 2);
    s += __shfl_xor(s, 4); s += __shfl_xor(s, 8);
    if ((t & 15) == 0) cw_s[arow] = s;
  }
  // spill sim (+qw) to LDS
#pragma unroll
  for (int j = 0; j < 2; ++j) {
    int col = wv * 32 + j * 16 + rl;
    float qv = qw_s[col];
    int rbase = kq * 4;
#pragma unroll
    for (int r = 0; r < 4; ++r) sim_s[rbase + r][col] = acc[j][r] + qv;
  }
  __syncthreads();
  // softmax over q: 16 threads/row, 8 cols each
  {
    int row = t >> 4, cb = t & 15;
    float v[8];
    float mx = -3.4e38f;
#pragma unroll
    for (int k = 0; k < 8; ++k) {
      v[k] = sim_s[row][cb + 16 * k];
      mx = fmaxf(mx, v[k]);
    }
    mx = fmaxf(mx, __shfl_xor(mx, 1));
    mx = fmaxf(mx, __shfl_xor(mx, 2));
    mx = fmaxf(mx, __shfl_xor(mx, 4));
    mx = fmaxf(mx, __shfl_xor(mx, 8));
    float sm = 0.f;
#pragma unroll
    for (int k = 0; k < 8; ++k) { v[k] = __expf(v[k] - mx); sm += v[k]; }
    sm += __shfl_xor(sm, 1);
    sm += __shfl_xor(sm, 2);
    sm += __shfl_xor(sm, 4);
    sm += __shfl_xor(sm, 8);
    float inv = 1.0f / sm;
#pragma unroll
    for (int k = 0; k < 8; ++k) P_lds[row][cb + 16 * k] = (bf16)(v[k] * inv);
    if (cb == 0) smax[b * CC + m0 + row] = mx + cw_s[row];
  }
  __syncthreads();  // P ready; sim_s dead -> U reusable by c2q_lds
  // stage 2: c2q(16x512) = P(16x128) @ qT(512x128)^T ; wave wv -> 128 cols
  f32x4 acc2[8] = {};
  const bf16* qTb = qT + (size_t)b * EE * QQ;
#pragma unroll
  for (int kk = 0; kk < 4; ++kk) {
    bf16x8 af2;
    {
      bf16x4 lo = *(const bf16x4*)&P_lds[rl][kk * 32 + kq * 8];
      bf16x4 hi = *(const bf16x4*)&P_lds[rl][kk * 32 + kq * 8 + 4];
      af2[0] = lo[0]; af2[1] = lo[1]; af2[2] = lo[2]; af2[3] = lo[3];
      af2[4] = hi[0]; af2[5] = hi[1]; af2[6] = hi[2]; af2[7] = hi[3];
    }
#pragma unroll
    for (int j = 0; j < 8; ++j) {
      int n = wv * 128 + j * 16 + rl;
      bf16x8 bfr = *(const bf16x8*)&qTb[(size_t)n * QQ + kk * 32 + kq * 8];
      acc2[j] = __builtin_amdgcn_mfma_f32_16x16x32_bf16(af2, bfr, acc2[j], 0, 0, 0);
    }
  }
  // spill c2q frags to LDS (row-major, stride 520)
#pragma unroll
  for (int j = 0; j < 8; ++j) {
    int col = wv * 128 + j * 16 + rl;
    int rbase = kq * 4;
#pragma unroll
    for (int r = 0; r < 4; ++r)
      c2q_lds[(size_t)(rbase + r) * 520 + col] = (bf16)acc2[j][r];
  }
  __syncthreads();
  // att epilogue: 16 rows x 512 cols, parts 0..2; 16 lanes cover 256B contig.
  {
    int row = t >> 4, tc = t & 15;
    const float* crow = ctx + ((size_t)(b * CC + m0 + row)) * EE;
    bf16* arow_p = att + ((size_t)(b * CC + m0 + row)) * FOURE;
#pragma unroll
    for (int cc = 0; cc < 4; ++cc) {
      int col = cc * 128 + tc * 8;
      bf16x8 q8 = *(const bf16x8*)&c2q_lds[(size_t)row * 520 + col];
      float4 v0 = *(const float4*)&crow[col];
      float4 v1 = *(const float4*)&crow[col + 4];
      float cv[8] = {v0.x, v0.y, v0.z, v0.w, v1.x, v1.y, v1.z, v1.w};
      bf16x8 o0, o2;
#pragma unroll
      for (int k = 0; k < 8; ++k) {
        o0[k] = (bf16)cv[k];
        o2[k] = (bf16)(cv[k] * (float)q8[k]);
      }
      *(bf16x8*)&arow_p[col] = o0;
      *(bf16x8*)&arow_p[EE + col] = q8;
      *(bf16x8*)&arow_p[2 * EE + col] = o2;
    }
  }
}

// ---------------------------------------------------------------------------
// q2c with fused (redundant per-block) softmax over c. Grid 256 = 8b x 32.
// atomicAdd into pre-zeroed q2c.
// ---------------------------------------------------------------------------
__global__ __launch_bounds__(256) void q2c_kernel(
    const float* __restrict__ ctx, const float* __restrict__ smax,
    float* __restrict__ q2c) {
  int b = blockIdx.x >> 5, ch = blockIdx.x & 31;
  int t = threadIdx.x;
  __shared__ float red[256];
  __shared__ float w_s[32];
  float v[4];
  float mx = -3.4e38f;
#pragma unroll
  for (int i = 0; i < 4; ++i) {
    v[i] = smax[b * CC + i * 256 + t];
    mx = fmaxf(mx, v[i]);
  }
  red[t] = mx;
  __syncthreads();
  for (int s = 128; s > 0; s >>= 1) {
    if (t < s) red[t] = fmaxf(red[t], red[t + s]);
    __syncthreads();
  }
  mx = red[0];
  __syncthreads();
  float sm = 0.f;
#pragma unroll
  for (int i = 0; i < 4; ++i) sm += __expf(v[i] - mx);
  red[t] = sm;
  __syncthreads();
  for (int s = 128; s > 0; s >>= 1) {
    if (t < s) red[t] += red[t + s];
    __syncthreads();
  }
  float inv = 1.0f / red[0];
  if (t < 32) w_s[t] = __expf(smax[b * CC + ch * 32 + t] - mx) * inv;
  __syncthreads();
  int e = t * 2;
  const float* cb = ctx + ((size_t)b * CC + ch * 32) * EE;
  float a0 = 0.f, a1 = 0.f;
#pragma unroll 8
  for (int r = 0; r < 32; ++r) {
    float2 vv = *(const float2*)&cb[(size_t)r * EE + e];
    float w = w_s[r];
    a0 += w * vv.x;
    a1 += w * vv.y;
  }
  atomicAdd(&q2c[b * EE + e], a0);
  atomicAdd(&q2c[b * EE + e + 1], a1);
}

// ---------------------------------------------------------------------------
// att part 3: att[:, 3E:4E] = ctx * q2c[b]  (BW-bound)
// ---------------------------------------------------------------------------
__global__ __launch_bounds__(256) void att3_kernel(
    const float* __restrict__ ctx, const float* __restrict__ q2c,
    bf16* __restrict__ att) {
  int idx = blockIdx.x * 256 + threadIdx.x;  // over (row, e/8)
  int row = idx >> 6;
  int e = (idx & 63) * 8;
  int b = row >> 10;
  float4 v0 = *(const float4*)&ctx[(size_t)row * EE + e];
  float4 v1 = *(const float4*)&ctx[(size_t)row * EE + e + 4];
  float4 g0 = *(const float4*)&q2c[b * EE + e];
  float4 g1 = *(const float4*)&q2c[b * EE + e + 4];
  bf16x8 o;
  o[0] = (bf16)(v0.x * g0.x); o[1] = (bf16)(v0.y * g0.y);
  o[2] = (bf16)(v0.z * g0.z); o[3] = (bf16)(v0.w * g0.w);
  o[4] = (bf16)(v1.x * g1.x); o[5] = (bf16)(v1.y * g1.y);
  o[6] = (bf16)(v1.z * g1.z); o[7] = (bf16)(v1.w * g1.w);
  *(bf16x8*)&att[(size_t)row * FOURE + 3 * EE + e] = o;
}

// ---------------------------------------------------------------------------
// bf16 GEMM (16x16x32, conflict-free): C = A(MxK) @ Bt(NxK)^T.
// Tile MT x 128, BK=64, async staging + XOR chunk-swizzle, GROUP_M=8.
// ---------------------------------------------------------------------------
template <int MT, int OUT_BF16, int RELU, int HAS_BIAS, int HAS_MASK>
__global__ __launch_bounds__(256) void gemm_bt_kernel(
    const bf16* __restrict__ A, const bf16* __restrict__ Bt,
    const float* __restrict__ bias, const float* __restrict__ mask,
    void* __restrict__ Cout, int M, int N, int K, long sA, long sB, long sC) {
  int b = blockIdx.y;
  A += (size_t)b * sA;
  Bt += (size_t)b * sB;
  int ntiles = N >> 7;
  int tiles_per_g = 8 * ntiles;
  int g = blockIdx.x / tiles_per_g, sub = blockIdx.x % tiles_per_g;
  int mt = g * 8 + (sub & 7), ntb = sub >> 3;
  int m0 = mt * MT, n0 = ntb << 7;
  __shared__ bf16 As[MT * 64];
  __shared__ bf16 Bs[128 * 64];
  int t = threadIdx.x, wv = t >> 6, ln = t & 63;
  int wm = wv >> 1, wn = wv & 1;
  constexpr int MI = MT / 32;
  f32x4 acc[MI][4] = {};
  for (int k0 = 0; k0 < K; k0 += 64) {
#pragma unroll
    for (int r = 0; r < MT / 32; ++r) {
      int fb = (r * 4 + wv) * 1024 + ln * 16;
      int row = fb >> 7;
      int q = ((fb >> 4) & 7) ^ (row & 7);
      async_copy16(A + (size_t)(m0 + row) * K + k0 + q * 8,
                   (char*)As + fb);
    }
#pragma unroll
    for (int r = 0; r < 4; ++r) {
      int fb = (r * 4 + wv) * 1024 + ln * 16;
      int row = fb >> 7;
      int q = ((fb >> 4) & 7) ^ (row & 7);
      async_copy16(Bt + (size_t)(n0 + row) * K + k0 + q * 8,
                   (char*)Bs + fb);
    }
    __syncthreads();
    int rl = ln & 15, kq = ln >> 4;
#pragma unroll
    for (int ks = 0; ks < 2; ++ks) {
      int c = ks * 4 + kq;
      bf16x8 af[MI], bfr[4];
#pragma unroll
      for (int i = 0; i < MI; ++i) {
        int row = wm * (MT / 2) + i * 16 + rl;
        af[i] = *(const bf16x8*)&As[row * 64 + ((c ^ (row & 7)) * 8)];
      }
#pragma unroll
      for (int j = 0; j < 4; ++j) {
        int row = wn * 64 + j * 16 + rl;
        bfr[j] = *(const bf16x8*)&Bs[row * 64 + ((c ^ (row & 7)) * 8)];
      }
#pragma unroll
      for (int i = 0; i < MI; ++i)
#pragma unroll
        for (int j = 0; j < 4; ++j)
          acc[i][j] = __builtin_amdgcn_mfma_f32_16x16x32_bf16(af[i], bfr[j], acc[i][j], 0, 0, 0);
    }
    __syncthreads();
  }
  size_t outbase = (size_t)b * sC;
#pragma unroll
  for (int j = 0; j < 4; ++j) {
    int col = n0 + wn * 64 + j * 16 + (ln & 15);
    float bv = HAS_BIAS ? bias[col] : 0.f;
#pragma unroll
    for (int i = 0; i < MI; ++i) {
      int rbase = m0 + wm * (MT / 2) + i * 16 + ((ln >> 4) << 2);
#pragma unroll
      for (int r = 0; r < 4; ++r) {
        int row = rbase + r;
        float v = acc[i][j][r] + bv;
        if (HAS_MASK) v *= mask[row];
        if (RELU) v = fmaxf(v, 0.f);
        if (OUT_BF16)
          ((bf16*)Cout)[outbase + (size_t)row * N + col] = (bf16)v;
        else
          ((float*)Cout)[outbase + (size_t)row * N + col] = v;
      }
    }
  }
}

// ---------------------------------------------------------------------------
// launcher — 6 kernels + 1 memset
// ---------------------------------------------------------------------------
extern "C" void kernel_launch(void* const* d_in, const int* in_sizes, int n_in,
                              void* d_out, int out_size, void* d_ws, size_t ws_size,
                              hipStream_t stream) {
  const float* ctx = (const float*)d_in[0];
  const float* qst = (const float*)d_in[1];
  const float* mask = (const float*)d_in[2];
  const float* wqv = (const float*)d_in[3];
  const float* wcv = (const float*)d_in[4];
  const float* wmul = (const float*)d_in[5];
  const float* W1 = (const float*)d_in[6];
  const float* b1 = (const float*)d_in[7];
  const float* W2 = (const float*)d_in[8];
  const float* b2 = (const float*)d_in[9];
  float* out = (float*)d_out;
  char* ws = (char*)d_ws;

  bf16* att = (bf16*)(ws);                  // 33554432
  bf16* hbuf = (bf16*)(ws + 33554432);      // 16777216
  bf16* W1T = (bf16*)(ws + 50331648);       // 4194304
  bf16* W2T = (bf16*)(ws + 54525952);       // 4194304
  bf16* qT = (bf16*)(ws + 58720256);        // 1048576
  bf16* qmh = (bf16*)(ws + 59768832);       // 1048576
  bf16* qml = (bf16*)(ws + 60817408);       // 1048576
  float* smax = (float*)(ws + 61865984);    // 32768
  float* q2c = (float*)(ws + 61898752);     // 16384
  float* qw = (float*)(ws + 61915136);      // 4096

  prep_kernel<<<5120, 256, 0, stream>>>(W1, W2, qst, wmul, wqv,
                                        W1T, W2T, qT, qmh, qml, qw);
  fused_att_kernel<<<dim3(64, BB), 256, 0, stream>>>(ctx, qmh, qml, qT, wcv,
                                                     qw, smax, att);
  hipMemsetAsync(q2c, 0, BB * EE * sizeof(float), stream);
  q2c_kernel<<<256, 256, 0, stream>>>(ctx, smax, q2c);
  att3_kernel<<<2048, 256, 0, stream>>>(ctx, q2c, att);
  gemm_bt_kernel<128, 1, 0, 1, 1><<<dim3(512, 1), 256, 0, stream>>>(
      att, W1T, b1, mask, hbuf, 8192, 1024, 2048, 0, 0, 0);
  gemm_bt_kernel<128, 0, 1, 1, 1><<<dim3(1024, 1), 256, 0, stream>>>(
      hbuf, W2T, b2, mask, out, 8192, 2048, 1024, 0, 0, 0);
}